// Round 26
// baseline (177.799 us; speedup 1.0000x reference)
//
#include <hip/hip_runtime.h>
#include <hip/hip_bf16.h>

typedef unsigned short u16;
typedef __attribute__((ext_vector_type(8))) short bf16x8;
typedef __attribute__((ext_vector_type(4))) float f32x4;
typedef __attribute__((ext_vector_type(16))) float f32x16;

#define DEVINL __device__ __forceinline__

struct alignas(16) U8 { u16 v[8]; };

DEVINL u16 f2bf(float f) {
    unsigned int x = __float_as_uint(f);
    unsigned int r = (x + 0x7fffu + ((x >> 16) & 1u)) >> 16;
    return (u16)r;
}

DEVINL void gload_lds16(const void* g, void* l) {
    __builtin_amdgcn_global_load_lds(
        (const __attribute__((address_space(1))) void*)g,
        (__attribute__((address_space(3))) void*)l,
        16, 0, 0);
}

// ---------------------------------------------------------------------------
// conversion kernel v4 (frozen): blocks 0..255 = h (+ act zeroing); rest x/W
// ---------------------------------------------------------------------------
__global__ __launch_bounds__(256) void cvt_all_kernel(
    const float* __restrict__ x, u16* __restrict__ xb,
    const float* __restrict__ wi, u16* __restrict__ wib,
    const float* __restrict__ wh, u16* __restrict__ whb,
    const float* __restrict__ wo, u16* __restrict__ wob,
    const float* __restrict__ h, u16* __restrict__ hbf,
    float* __restrict__ partial, float* __restrict__ act) {
    int b = blockIdx.x;
    int t = threadIdx.x;
    if (b < 256) {
        if (t < 8) act[b * 8 + t] = 0.f;
        float cnt[8] = {0.f, 0.f, 0.f, 0.f, 0.f, 0.f, 0.f, 0.f};
#pragma unroll 4
        for (int r = 0; r < 32; ++r) {
            size_t off = ((size_t)(b * 32 + r)) * 2048 + t * 8;
            float4 a = *(const float4*)(h + off);
            float4 bb = *(const float4*)(h + off + 4);
            float vv[8] = {a.x, a.y, a.z, a.w, bb.x, bb.y, bb.z, bb.w};
            U8 u;
#pragma unroll
            for (int j = 0; j < 8; ++j) {
                u.v[j] = f2bf(vv[j]);
                cnt[j] += (fabsf(vv[j]) > 0.1f) ? 1.f : 0.f;
            }
            *(U8*)(hbf + off) = u;
        }
        float4 p0 = {cnt[0], cnt[1], cnt[2], cnt[3]};
        float4 p1 = {cnt[4], cnt[5], cnt[6], cnt[7]};
        *(float4*)(partial + (size_t)b * 2048 + t * 8) = p0;
        *(float4*)(partial + (size_t)b * 2048 + t * 8 + 4) = p1;
    } else {
        int i = (b - 256) * 256 + t;
        const float* src; u16* dst; int off;
        if (i < 1048576)       { src = x;  dst = xb;  off = i; }
        else if (i < 1310720)  { src = wi; dst = wib; off = i - 1048576; }
        else if (i < 1835008)  { src = wh; dst = whb; off = i - 1310720; }
        else                   { src = wo; dst = wob; off = i - 1835008; }
        const float4* p = (const float4*)src + (size_t)off * 2;
        float4 a = p[0], bb = p[1];
        U8 u;
        u.v[0] = f2bf(a.x);  u.v[1] = f2bf(a.y);  u.v[2] = f2bf(a.z);  u.v[3] = f2bf(a.w);
        u.v[4] = f2bf(bb.x); u.v[5] = f2bf(bb.y); u.v[6] = f2bf(bb.z); u.v[7] = f2bf(bb.w);
        *(U8*)(dst + (size_t)off * 8) = u;
    }
}

// ---------------------------------------------------------------------------
// staging helpers (frozen structure; swizzle passed in via lo)
// ---------------------------------------------------------------------------
DEVINL void stA(const u16* p, int uni, int lo, int ld, u16* dst, int w) {
    gload_lds16(p + uni + lo, dst + ((w << 3) << 6));
    gload_lds16(p + uni + lo + (ld << 7), dst + ((128 + (w << 3)) << 6));
}
DEVINL void stB(const u16* p, int uni, int lo, int ld, u16* dst, int w) {
    int d0 = ((w >> 2) << 6) + ((w & 3) << 3);
    gload_lds16(p + uni + lo, dst + (d0 << 6));
    gload_lds16(p + uni + lo + (ld << 7), dst + ((128 + d0) << 6));
}

struct SegU { const u16* pA; const u16* pB; int uA; int uB; int ld; int loA; int loB; };

DEVINL SegU segu(int kt, const u16* X, const u16* W1, const u16* H, const u16* W2,
                 int rbA, int rbB, int loA1, int loA2, int loB1, int loB2) {
    SegU s;
    if (kt < 16) {
        int k0 = kt << 6;
        s.pA = X; s.pB = W1; s.ld = 1024;
        s.uA = (rbA << 10) + k0; s.uB = (rbB << 10) + k0;
        s.loA = loA1; s.loB = loB1;
    } else {
        int k0 = (kt - 16) << 6;
        s.pA = H; s.pB = W2; s.ld = 2048;
        s.uA = (rbA << 11) + k0; s.uB = (rbB << 11) + k0;
        s.loA = loA2; s.loB = loB2;
    }
    return s;
}

#define STA(S, SET, BUF) stA((S).pA, (S).uA + ((SET) ? ((S).ld << 6) : 0), (S).loA, \
                             (S).ld, Alds + (BUF) * 16384 + (SET) * 4096, w)
#define STB(S, SET, BUF) stB((S).pB, (S).uB + ((SET) ? ((S).ld << 5) : 0), (S).loB, \
                             (S).ld, Blds + (BUF) * 16384 + (SET) * 2048, w)

// 32x32x16 fragment reads: per-kk base pointer + imm
#define RD_A32(MQ, BUF) do { \
    _Pragma("unroll") for (int kk = 0; kk < 4; ++kk) \
    _Pragma("unroll") for (int mi = 0; mi < 2; ++mi) \
        afr[mi][kk] = *(const bf16x8*)(fAk[kk] + (BUF) * 32768 + ((MQ)*2 + mi) * 4096); \
    } while (0)

#define RD_B_ALL32(BUF) do { \
    _Pragma("unroll") for (int kk = 0; kk < 4; ++kk) \
    _Pragma("unroll") for (int nj = 0; nj < 2; ++nj) \
        bfr[nj][kk] = *(const bf16x8*)(fBk[kk] + (BUF) * 32768 + nj * 4096); \
    } while (0)

// 16 MFMA 32x32x16: one m-half (2 mi) x 2 nj x 4 kk
#define MFMA_M32(MQ) do { \
    _Pragma("unroll") for (int mi = 0; mi < 2; ++mi) \
    _Pragma("unroll") for (int nj = 0; nj < 2; ++nj) \
    _Pragma("unroll") for (int kk = 0; kk < 4; ++kk) \
        acc[(MQ)*2 + mi][nj] = __builtin_amdgcn_mfma_f32_32x32x16_bf16( \
            afr[mi][kk], bfr[nj][kk], acc[(MQ)*2 + mi][nj], 0, 0, 0); \
    } while (0)

#define PHASE_MID() do { \
    asm volatile("s_waitcnt lgkmcnt(0)" ::: "memory"); \
    __builtin_amdgcn_sched_barrier(0); \
    __builtin_amdgcn_s_setprio(1); \
    } while (0)

#define BAREND() do { \
    __builtin_amdgcn_s_setprio(0); \
    __builtin_amdgcn_sched_barrier(0); \
    asm volatile("s_barrier" ::: "memory"); \
    } while (0)

#define BAREND_VM() do { \
    __builtin_amdgcn_s_setprio(0); \
    __builtin_amdgcn_sched_barrier(0); \
    asm volatile("s_waitcnt vmcnt(4)" ::: "memory"); \
    asm volatile("s_barrier" ::: "memory"); \
    } while (0)

#define BAREND_VM3() do { \
    __builtin_amdgcn_s_setprio(0); \
    __builtin_amdgcn_sched_barrier(0); \
    asm volatile("s_waitcnt vmcnt(3)" ::: "memory"); \
    asm volatile("s_barrier" ::: "memory"); \
    } while (0)

// ---------------------------------------------------------------------------
// GEMM12 with 32x32x16 MFMA, conflict-free 5-bit involution (frozen, measured)
// ---------------------------------------------------------------------------
__global__ __launch_bounds__(512, 2) void gemm12_k8(
    const u16* __restrict__ Xbf, const u16* __restrict__ Win,
    const u16* __restrict__ Hbf, const u16* __restrict__ Whh,
    const float* __restrict__ bh,
    float* __restrict__ hnew_f32, u16* __restrict__ hnew_bf,
    float* __restrict__ act_out,
    const float* __restrict__ partial, float* __restrict__ rec_out) {
    __shared__ alignas(16) u16 lds[4][16384];  // [A0|A1|B0|B1] = 128 KB
    u16* Alds = &lds[0][0];
    u16* Blds = &lds[2][0];
    int orig = blockIdx.x;
    int wg = (orig & 7) * 32 + (orig >> 3);    // XCD swizzle
    int bm = wg >> 3, bn = wg & 7;
    int t = threadIdx.x, lane = t & 63, w = t >> 6;
    int wm = w >> 2, wn = w & 3;
    int l31 = lane & 31, hi32 = lane >> 5;
    int rbA = bm << 8, rbB = bn << 8;

    // folded rec final reduce: block handles cols [orig*8, orig*8+8)
    {
        int col = (orig << 3) + (t >> 6);
        float s = partial[(size_t)lane * 2048 + col]
                + partial[(size_t)(lane + 64) * 2048 + col]
                + partial[(size_t)(lane + 128) * 2048 + col]
                + partial[(size_t)(lane + 192) * 2048 + col];
#pragma unroll
        for (int o = 1; o < 64; o <<= 1) s += __shfl_xor(s, o, 64);
        if (lane == 0) rec_out[col] = s * (1.0f / 8192.0f);
    }

    // staging lane offsets; 5-bit involution, r0-invariant for both ops
    int r0 = t >> 3, c8 = t & 7;
    int swz = ((c8 ^ (r0 & 7) ^ ((r0 >> 3) & 3))) << 3;
    int arB0 = ((r0 >> 5) << 6) + (r0 & 31);
    int loA1 = (r0 << 10) + swz, loA2 = (r0 << 11) + swz;
    int loB1 = (arB0 << 10) + swz, loB2 = (arB0 << 11) + swz;

    // 32x32 fragment base pointers, one per kk (read swizzle matches staging)
    const char* fAk[4];
    const char* fBk[4];
#pragma unroll
    for (int kk = 0; kk < 4; ++kk) {
        int cb = ((kk << 1) + hi32) ^ (l31 & 7) ^ ((l31 >> 3) & 3);
        fAk[kk] = (const char*)(Alds + (((wm << 7) + l31) << 6)) + (cb << 4);
        fBk[kk] = (const char*)(Blds + (((wn << 6) + l31) << 6)) + (cb << 4);
    }

    f32x16 acc[4][2];
    f32x16 zf = {};
#pragma unroll
    for (int i = 0; i < 4; ++i)
#pragma unroll
        for (int j = 0; j < 2; ++j) acc[i][j] = zf;
    bf16x8 afr[2][4], bfr[2][4];

    // prologue (frozen ledger): 12 loads, wait to <=4
    {
        SegU s0 = segu(0, Xbf, Win, Hbf, Whh, rbA, rbB, loA1, loA2, loB1, loB2);
        SegU s1 = segu(1, Xbf, Win, Hbf, Whh, rbA, rbB, loA1, loA2, loB1, loB2);
        STA(s0, 0, 0); STB(s0, 0, 0);
        STA(s0, 1, 0); STB(s0, 1, 0);
        STA(s1, 0, 1); STB(s1, 0, 1);
    }
    asm volatile("s_waitcnt vmcnt(4)" ::: "memory");
    asm volatile("s_barrier" ::: "memory");

    for (int it = 0; it < 24; ++it) {
        int tb = it << 1;
        int t2 = tb + 2 < 47 ? tb + 2 : 47;
        int t3 = tb + 3 < 47 ? tb + 3 : 47;
        SegU s1 = segu(tb + 1, Xbf, Win, Hbf, Whh, rbA, rbB, loA1, loA2, loB1, loB2);
        SegU s2 = segu(t2,     Xbf, Win, Hbf, Whh, rbA, rbB, loA1, loA2, loB1, loB2);
        SegU s3 = segu(t3,     Xbf, Win, Hbf, Whh, rbA, rbB, loA1, loA2, loB1, loB2);

        // phase A: tile tb (buf0), m0; stage (tb+1,set1)->buf1
        RD_B_ALL32(0); RD_A32(0, 0);
        STA(s1, 1, 1); STB(s1, 1, 1);
        PHASE_MID(); MFMA_M32(0); BAREND();
        // phase B: tile tb, m1; stage (tb+2,set0)->buf0
        RD_A32(1, 0);
        STA(s2, 0, 0); STB(s2, 0, 0);
        PHASE_MID(); MFMA_M32(1); BAREND_VM();
        // phase C: tile tb+1 (buf1), m0; stage (tb+2,set1)->buf0
        RD_B_ALL32(1); RD_A32(0, 1);
        STA(s2, 1, 0); STB(s2, 1, 0);
        PHASE_MID(); MFMA_M32(0); BAREND();
        // phase D: tile tb+1, m1; stage (tb+3,set0)->buf1
        RD_A32(1, 1);
        STA(s3, 0, 1); STB(s3, 0, 1);
        PHASE_MID(); MFMA_M32(1); BAREND_VM();
    }

    // epilogue: 32x32 C/D layout: col = lane&31, row = (q&3)+8*(q>>2)+4*(lane>>5)
    const int row0 = (bm << 8) + (wm << 7);
    const int col0 = (bn << 8) + (wn << 6);
#pragma unroll
    for (int nj = 0; nj < 2; ++nj) {
        int col = col0 + (nj << 5) + l31;
        float bhv = bh[col];
        float csum = 0.f;
#pragma unroll
        for (int mi = 0; mi < 4; ++mi) {
#pragma unroll
            for (int q = 0; q < 16; ++q) {
                int row = row0 + (mi << 5) + (q & 3) + ((q >> 2) << 3) + (hi32 << 2);
                float v = fmaxf(acc[mi][nj][q] + bhv, 0.f);
                size_t off = (size_t)row * 2048 + col;
                hnew_f32[off] = v;
                hnew_bf[off] = f2bf(v);
                csum += v;
            }
        }
        csum += __shfl_xor(csum, 32, 64);
        if (lane < 32) atomicAdd(&act_out[col], csum * (1.0f / 8192.0f));
    }
}

// ---------------------------------------------------------------------------
// GEMM3 with 32x32x16 MFMA + 5-bit involution (cloned from proven gemm12)
// 256x128 tile, 8 waves (2Mx4N), per-wave 128x32: 4 mi x 1 nj, 4 kk
// ---------------------------------------------------------------------------
#define G3_STA(KT, SET, BUF) do { \
    int uni_ = uA + ((KT) << 6) + ((SET) ? (2048 << 6) : 0); \
    u16* dst_ = g3A + (BUF) * 16384 + (SET) * 4096; \
    gload_lds16(Hn + uni_ + lo, dst_ + ((w << 3) << 6)); \
    gload_lds16(Hn + uni_ + lo + (2048 << 7), dst_ + ((128 + (w << 3)) << 6)); \
    } while (0)

#define G3_STB(KT, SET, BUF) do { \
    int uni_ = uB + ((KT) << 6) + ((SET) ? (2048 << 6) : 0); \
    gload_lds16(Wout + uni_ + lo, g3B + (BUF) * 8192 + (SET) * 4096 + ((w << 3) << 6)); \
    } while (0)

#define G3_RD_A32(MQ, BUF) do { \
    _Pragma("unroll") for (int kk = 0; kk < 4; ++kk) \
    _Pragma("unroll") for (int mi = 0; mi < 2; ++mi) \
        afr[mi][kk] = *(const bf16x8*)(gAk[kk] + (BUF) * 32768 + ((MQ)*2 + mi) * 4096); \
    } while (0)

#define G3_RD_B32(BUF) do { \
    _Pragma("unroll") for (int kk = 0; kk < 4; ++kk) \
        bfr[kk] = *(const bf16x8*)(gBk[kk] + (BUF) * 16384); \
    } while (0)

#define G3_MFMA32(MQ) do { \
    _Pragma("unroll") for (int mi = 0; mi < 2; ++mi) \
    _Pragma("unroll") for (int kk = 0; kk < 4; ++kk) \
        acc3[(MQ)*2 + mi] = __builtin_amdgcn_mfma_f32_32x32x16_bf16( \
            afr[mi][kk], bfr[kk], acc3[(MQ)*2 + mi], 0, 0, 0); \
    } while (0)

__global__ __launch_bounds__(512, 1) void gemm3_k8(
    const u16* __restrict__ Hn, const u16* __restrict__ Wout,
    const float* __restrict__ bout, float* __restrict__ y) {
    __shared__ alignas(16) u16 lds[49152];  // A: 2x16384, B: 2x8192 = 96 KB
    u16* g3A = &lds[0];
    u16* g3B = &lds[32768];
    int orig = blockIdx.x;
    int wg = (orig & 7) * 32 + (orig >> 3);
    int bm = wg >> 3, bn = wg & 7;
    int t = threadIdx.x, lane = t & 63, w = t >> 6;
    int wm = w >> 2, wn = w & 3;
    int l31 = lane & 31, hi32 = lane >> 5;

    // staging lane offsets with 5-bit involution (r0-invariant per round-25 audit)
    int r0 = t >> 3, c8 = t & 7;
    int swz = ((c8 ^ (r0 & 7) ^ ((r0 >> 3) & 3))) << 3;
    int lo = (r0 << 11) + swz;
    int uA = (bm << 8) << 11;
    int uB = (bn << 7) << 11;

    // 32x32 fragment bases per kk (read swizzle matches staging involution)
    const char* gAk[4];
    const char* gBk[4];
#pragma unroll
    for (int kk = 0; kk < 4; ++kk) {
        int cb = ((kk << 1) + hi32) ^ (l31 & 7) ^ ((l31 >> 3) & 3);
        gAk[kk] = (const char*)(g3A + (((wm << 7) + l31) << 6)) + (cb << 4);
        gBk[kk] = (const char*)(g3B + (((wn << 5) + l31) << 6)) + (cb << 4);
    }

    f32x16 acc3[4];
    f32x16 zf = {};
#pragma unroll
    for (int i = 0; i < 4; ++i) acc3[i] = zf;
    bf16x8 afr[2][4], bfr[4];

    // prologue: tile0 full (6 loads) + tile1 set0 (3 loads); wait to <=3
    G3_STA(0, 0, 0); G3_STB(0, 0, 0);
    G3_STA(0, 1, 0); G3_STB(0, 1, 0);
    G3_STA(1, 0, 1); G3_STB(1, 0, 1);
    asm volatile("s_waitcnt vmcnt(3)" ::: "memory");
    asm volatile("s_barrier" ::: "memory");

    for (int it = 0; it < 16; ++it) {
        int tb = it << 1;
        int t2 = tb + 2 < 31 ? tb + 2 : 31;
        int t3 = tb + 3 < 31 ? tb + 3 : 31;
        int t1 = tb + 1;

        // phase A: tile tb (buf0), m0; stage (tb+1,set1)->buf1
        G3_RD_B32(0); G3_RD_A32(0, 0);
        G3_STA(t1, 1, 1); G3_STB(t1, 1, 1);
        PHASE_MID(); G3_MFMA32(0); BAREND();
        // phase B: tile tb, m1; stage (tb+2,set0)->buf0
        G3_RD_A32(1, 0);
        G3_STA(t2, 0, 0); G3_STB(t2, 0, 0);
        PHASE_MID(); G3_MFMA32(1); BAREND_VM3();
        // phase C: tile tb+1 (buf1), m0; stage (tb+2,set1)->buf0
        G3_RD_B32(1); G3_RD_A32(0, 1);
        G3_STA(t2, 1, 0); G3_STB(t2, 1, 0);
        PHASE_MID(); G3_MFMA32(0); BAREND();
        // phase D: tile tb+1, m1; stage (tb+3,set0)->buf1
        G3_RD_A32(1, 1);
        G3_STA(t3, 0, 1); G3_STB(t3, 0, 1);
        PHASE_MID(); G3_MFMA32(1); BAREND_VM3();
    }

    // epilogue: 32x32 C/D layout
    const int row0 = (bm << 8) + (wm << 7);
    const int col = (bn << 7) + (wn << 5) + l31;
    float bv = bout[col];
#pragma unroll
    for (int mi = 0; mi < 4; ++mi) {
#pragma unroll
        for (int q = 0; q < 16; ++q) {
            int row = row0 + (mi << 5) + (q & 3) + ((q >> 2) << 3) + (hi32 << 2);
            y[(size_t)row * 1024 + col] = acc3[mi][q] + bv;
        }
    }
}

// ---------------------------------------------------------------------------
extern "C" void kernel_launch(void* const* d_in, const int* in_sizes, int n_in,
                              void* d_out, int out_size, void* d_ws, size_t ws_size,
                              hipStream_t stream) {
    const float* x     = (const float*)d_in[0];
    const float* h     = (const float*)d_in[1];
    const float* W_in  = (const float*)d_in[2];
    const float* W_hh  = (const float*)d_in[3];
    const float* b_h   = (const float*)d_in[4];
    const float* W_out = (const float*)d_in[5];
    const float* b_out = (const float*)d_in[6];

    float* out  = (float*)d_out;
    float* y    = out;
    float* hnew = out + 8388608;
    float* act  = out + 8388608 + 16777216;
    float* rec  = act + 2048;

    char* ws = (char*)d_ws;
    u16* x_bf    = (u16*)(ws);
    u16* h_bf    = (u16*)(ws + (16ull << 20));
    u16* win_bf  = (u16*)(ws + (48ull << 20));
    u16* whh_bf  = (u16*)(ws + (52ull << 20));
    u16* wout_bf = (u16*)(ws + (60ull << 20));
    u16* hn_bf   = (u16*)(ws + (64ull << 20));
    float* partial = (float*)(ws + (96ull << 20));  // 256 x 2048 f32 = 2 MB

    cvt_all_kernel<<<8448, 256, 0, stream>>>(x, x_bf, W_in, win_bf, W_hh, whh_bf,
                                             W_out, wout_bf, h, h_bf, partial, act);

    gemm12_k8<<<256, 512, 0, stream>>>(x_bf, win_bf, h_bf, whh_bf, b_h,
                                       hnew, hn_bf, act, partial, rec);
    gemm3_k8<<<256, 512, 0, stream>>>(hn_bf, wout_bf, b_out, y);
}

// Round 27
// 173.894 us; speedup vs baseline: 1.0225x; 1.0225x over previous
//
#include <hip/hip_runtime.h>
#include <hip/hip_bf16.h>

typedef unsigned short u16;
typedef __attribute__((ext_vector_type(8))) short bf16x8;
typedef __attribute__((ext_vector_type(4))) float f32x4;
typedef __attribute__((ext_vector_type(16))) float f32x16;

#define DEVINL __device__ __forceinline__

struct alignas(16) U8 { u16 v[8]; };

DEVINL u16 f2bf(float f) {
    unsigned int x = __float_as_uint(f);
    unsigned int r = (x + 0x7fffu + ((x >> 16) & 1u)) >> 16;
    return (u16)r;
}

DEVINL void gload_lds16(const void* g, void* l) {
    __builtin_amdgcn_global_load_lds(
        (const __attribute__((address_space(1))) void*)g,
        (__attribute__((address_space(3))) void*)l,
        16, 0, 0);
}

// ---------------------------------------------------------------------------
// conversion kernel v4 (frozen): blocks 0..255 = h (+ act zeroing); rest x/W
// ---------------------------------------------------------------------------
__global__ __launch_bounds__(256) void cvt_all_kernel(
    const float* __restrict__ x, u16* __restrict__ xb,
    const float* __restrict__ wi, u16* __restrict__ wib,
    const float* __restrict__ wh, u16* __restrict__ whb,
    const float* __restrict__ wo, u16* __restrict__ wob,
    const float* __restrict__ h, u16* __restrict__ hbf,
    float* __restrict__ partial, float* __restrict__ act) {
    int b = blockIdx.x;
    int t = threadIdx.x;
    if (b < 256) {
        if (t < 8) act[b * 8 + t] = 0.f;
        float cnt[8] = {0.f, 0.f, 0.f, 0.f, 0.f, 0.f, 0.f, 0.f};
#pragma unroll 4
        for (int r = 0; r < 32; ++r) {
            size_t off = ((size_t)(b * 32 + r)) * 2048 + t * 8;
            float4 a = *(const float4*)(h + off);
            float4 bb = *(const float4*)(h + off + 4);
            float vv[8] = {a.x, a.y, a.z, a.w, bb.x, bb.y, bb.z, bb.w};
            U8 u;
#pragma unroll
            for (int j = 0; j < 8; ++j) {
                u.v[j] = f2bf(vv[j]);
                cnt[j] += (fabsf(vv[j]) > 0.1f) ? 1.f : 0.f;
            }
            *(U8*)(hbf + off) = u;
        }
        float4 p0 = {cnt[0], cnt[1], cnt[2], cnt[3]};
        float4 p1 = {cnt[4], cnt[5], cnt[6], cnt[7]};
        *(float4*)(partial + (size_t)b * 2048 + t * 8) = p0;
        *(float4*)(partial + (size_t)b * 2048 + t * 8 + 4) = p1;
    } else {
        int i = (b - 256) * 256 + t;
        const float* src; u16* dst; int off;
        if (i < 1048576)       { src = x;  dst = xb;  off = i; }
        else if (i < 1310720)  { src = wi; dst = wib; off = i - 1048576; }
        else if (i < 1835008)  { src = wh; dst = whb; off = i - 1310720; }
        else                   { src = wo; dst = wob; off = i - 1835008; }
        const float4* p = (const float4*)src + (size_t)off * 2;
        float4 a = p[0], bb = p[1];
        U8 u;
        u.v[0] = f2bf(a.x);  u.v[1] = f2bf(a.y);  u.v[2] = f2bf(a.z);  u.v[3] = f2bf(a.w);
        u.v[4] = f2bf(bb.x); u.v[5] = f2bf(bb.y); u.v[6] = f2bf(bb.z); u.v[7] = f2bf(bb.w);
        *(U8*)(dst + (size_t)off * 8) = u;
    }
}

// ---------------------------------------------------------------------------
// staging helpers (frozen structure; swizzle passed in via lo)
// ---------------------------------------------------------------------------
DEVINL void stA(const u16* p, int uni, int lo, int ld, u16* dst, int w) {
    gload_lds16(p + uni + lo, dst + ((w << 3) << 6));
    gload_lds16(p + uni + lo + (ld << 7), dst + ((128 + (w << 3)) << 6));
}
DEVINL void stB(const u16* p, int uni, int lo, int ld, u16* dst, int w) {
    int d0 = ((w >> 2) << 6) + ((w & 3) << 3);
    gload_lds16(p + uni + lo, dst + (d0 << 6));
    gload_lds16(p + uni + lo + (ld << 7), dst + ((128 + d0) << 6));
}

struct SegU { const u16* pA; const u16* pB; int uA; int uB; int ld; int loA; int loB; };

DEVINL SegU segu(int kt, const u16* X, const u16* W1, const u16* H, const u16* W2,
                 int rbA, int rbB, int loA1, int loA2, int loB1, int loB2) {
    SegU s;
    if (kt < 16) {
        int k0 = kt << 6;
        s.pA = X; s.pB = W1; s.ld = 1024;
        s.uA = (rbA << 10) + k0; s.uB = (rbB << 10) + k0;
        s.loA = loA1; s.loB = loB1;
    } else {
        int k0 = (kt - 16) << 6;
        s.pA = H; s.pB = W2; s.ld = 2048;
        s.uA = (rbA << 11) + k0; s.uB = (rbB << 11) + k0;
        s.loA = loA2; s.loB = loB2;
    }
    return s;
}

#define STA(S, SET, BUF) stA((S).pA, (S).uA + ((SET) ? ((S).ld << 6) : 0), (S).loA, \
                             (S).ld, Alds + (BUF) * 16384 + (SET) * 4096, w)
#define STB(S, SET, BUF) stB((S).pB, (S).uB + ((SET) ? ((S).ld << 5) : 0), (S).loB, \
                             (S).ld, Blds + (BUF) * 16384 + (SET) * 2048, w)

// 32x32x16 fragment reads: per-kk base pointer + imm
#define RD_A32(MQ, BUF) do { \
    _Pragma("unroll") for (int kk = 0; kk < 4; ++kk) \
    _Pragma("unroll") for (int mi = 0; mi < 2; ++mi) \
        afr[mi][kk] = *(const bf16x8*)(fAk[kk] + (BUF) * 32768 + ((MQ)*2 + mi) * 4096); \
    } while (0)

#define RD_B_ALL32(BUF) do { \
    _Pragma("unroll") for (int kk = 0; kk < 4; ++kk) \
    _Pragma("unroll") for (int nj = 0; nj < 2; ++nj) \
        bfr[nj][kk] = *(const bf16x8*)(fBk[kk] + (BUF) * 32768 + nj * 4096); \
    } while (0)

// 16 MFMA 32x32x16: one m-half (2 mi) x 2 nj x 4 kk
#define MFMA_M32(MQ) do { \
    _Pragma("unroll") for (int mi = 0; mi < 2; ++mi) \
    _Pragma("unroll") for (int nj = 0; nj < 2; ++nj) \
    _Pragma("unroll") for (int kk = 0; kk < 4; ++kk) \
        acc[(MQ)*2 + mi][nj] = __builtin_amdgcn_mfma_f32_32x32x16_bf16( \
            afr[mi][kk], bfr[nj][kk], acc[(MQ)*2 + mi][nj], 0, 0, 0); \
    } while (0)

#define PHASE_MID() do { \
    asm volatile("s_waitcnt lgkmcnt(0)" ::: "memory"); \
    __builtin_amdgcn_sched_barrier(0); \
    __builtin_amdgcn_s_setprio(1); \
    } while (0)

#define BAREND() do { \
    __builtin_amdgcn_s_setprio(0); \
    __builtin_amdgcn_sched_barrier(0); \
    asm volatile("s_barrier" ::: "memory"); \
    } while (0)

#define BAREND_VM() do { \
    __builtin_amdgcn_s_setprio(0); \
    __builtin_amdgcn_sched_barrier(0); \
    asm volatile("s_waitcnt vmcnt(4)" ::: "memory"); \
    asm volatile("s_barrier" ::: "memory"); \
    } while (0)

#define BAREND_VM3() do { \
    __builtin_amdgcn_s_setprio(0); \
    __builtin_amdgcn_sched_barrier(0); \
    asm volatile("s_waitcnt vmcnt(3)" ::: "memory"); \
    asm volatile("s_barrier" ::: "memory"); \
    } while (0)

// ---------------------------------------------------------------------------
// GEMM12 with 32x32x16 MFMA, conflict-free 5-bit involution (frozen, measured)
// ---------------------------------------------------------------------------
__global__ __launch_bounds__(512, 2) void gemm12_k8(
    const u16* __restrict__ Xbf, const u16* __restrict__ Win,
    const u16* __restrict__ Hbf, const u16* __restrict__ Whh,
    const float* __restrict__ bh,
    float* __restrict__ hnew_f32, u16* __restrict__ hnew_bf,
    float* __restrict__ act_out,
    const float* __restrict__ partial, float* __restrict__ rec_out) {
    __shared__ alignas(16) u16 lds[4][16384];  // [A0|A1|B0|B1] = 128 KB
    u16* Alds = &lds[0][0];
    u16* Blds = &lds[2][0];
    int orig = blockIdx.x;
    int wg = (orig & 7) * 32 + (orig >> 3);    // XCD swizzle
    int bm = wg >> 3, bn = wg & 7;
    int t = threadIdx.x, lane = t & 63, w = t >> 6;
    int wm = w >> 2, wn = w & 3;
    int l31 = lane & 31, hi32 = lane >> 5;
    int rbA = bm << 8, rbB = bn << 8;

    // folded rec final reduce: block handles cols [orig*8, orig*8+8)
    {
        int col = (orig << 3) + (t >> 6);
        float s = partial[(size_t)lane * 2048 + col]
                + partial[(size_t)(lane + 64) * 2048 + col]
                + partial[(size_t)(lane + 128) * 2048 + col]
                + partial[(size_t)(lane + 192) * 2048 + col];
#pragma unroll
        for (int o = 1; o < 64; o <<= 1) s += __shfl_xor(s, o, 64);
        if (lane == 0) rec_out[col] = s * (1.0f / 8192.0f);
    }

    // staging lane offsets; 5-bit involution, r0-invariant for both ops
    int r0 = t >> 3, c8 = t & 7;
    int swz = ((c8 ^ (r0 & 7) ^ ((r0 >> 3) & 3))) << 3;
    int arB0 = ((r0 >> 5) << 6) + (r0 & 31);
    int loA1 = (r0 << 10) + swz, loA2 = (r0 << 11) + swz;
    int loB1 = (arB0 << 10) + swz, loB2 = (arB0 << 11) + swz;

    // 32x32 fragment base pointers, one per kk (read swizzle matches staging)
    const char* fAk[4];
    const char* fBk[4];
#pragma unroll
    for (int kk = 0; kk < 4; ++kk) {
        int cb = ((kk << 1) + hi32) ^ (l31 & 7) ^ ((l31 >> 3) & 3);
        fAk[kk] = (const char*)(Alds + (((wm << 7) + l31) << 6)) + (cb << 4);
        fBk[kk] = (const char*)(Blds + (((wn << 6) + l31) << 6)) + (cb << 4);
    }

    f32x16 acc[4][2];
    f32x16 zf = {};
#pragma unroll
    for (int i = 0; i < 4; ++i)
#pragma unroll
        for (int j = 0; j < 2; ++j) acc[i][j] = zf;
    bf16x8 afr[2][4], bfr[2][4];

    // prologue (frozen ledger): 12 loads, wait to <=4
    {
        SegU s0 = segu(0, Xbf, Win, Hbf, Whh, rbA, rbB, loA1, loA2, loB1, loB2);
        SegU s1 = segu(1, Xbf, Win, Hbf, Whh, rbA, rbB, loA1, loA2, loB1, loB2);
        STA(s0, 0, 0); STB(s0, 0, 0);
        STA(s0, 1, 0); STB(s0, 1, 0);
        STA(s1, 0, 1); STB(s1, 0, 1);
    }
    asm volatile("s_waitcnt vmcnt(4)" ::: "memory");
    asm volatile("s_barrier" ::: "memory");

    for (int it = 0; it < 24; ++it) {
        int tb = it << 1;
        int t2 = tb + 2 < 47 ? tb + 2 : 47;
        int t3 = tb + 3 < 47 ? tb + 3 : 47;
        SegU s1 = segu(tb + 1, Xbf, Win, Hbf, Whh, rbA, rbB, loA1, loA2, loB1, loB2);
        SegU s2 = segu(t2,     Xbf, Win, Hbf, Whh, rbA, rbB, loA1, loA2, loB1, loB2);
        SegU s3 = segu(t3,     Xbf, Win, Hbf, Whh, rbA, rbB, loA1, loA2, loB1, loB2);

        // phase A: tile tb (buf0), m0; stage (tb+1,set1)->buf1
        RD_B_ALL32(0); RD_A32(0, 0);
        STA(s1, 1, 1); STB(s1, 1, 1);
        PHASE_MID(); MFMA_M32(0); BAREND();
        // phase B: tile tb, m1; stage (tb+2,set0)->buf0
        RD_A32(1, 0);
        STA(s2, 0, 0); STB(s2, 0, 0);
        PHASE_MID(); MFMA_M32(1); BAREND_VM();
        // phase C: tile tb+1 (buf1), m0; stage (tb+2,set1)->buf0
        RD_B_ALL32(1); RD_A32(0, 1);
        STA(s2, 1, 0); STB(s2, 1, 0);
        PHASE_MID(); MFMA_M32(0); BAREND();
        // phase D: tile tb+1, m1; stage (tb+3,set0)->buf1
        RD_A32(1, 1);
        STA(s3, 0, 1); STB(s3, 0, 1);
        PHASE_MID(); MFMA_M32(1); BAREND_VM();
    }

    // epilogue: 32x32 C/D layout: col = lane&31, row = (q&3)+8*(q>>2)+4*(lane>>5)
    const int row0 = (bm << 8) + (wm << 7);
    const int col0 = (bn << 8) + (wn << 6);
#pragma unroll
    for (int nj = 0; nj < 2; ++nj) {
        int col = col0 + (nj << 5) + l31;
        float bhv = bh[col];
        float csum = 0.f;
#pragma unroll
        for (int mi = 0; mi < 4; ++mi) {
#pragma unroll
            for (int q = 0; q < 16; ++q) {
                int row = row0 + (mi << 5) + (q & 3) + ((q >> 2) << 3) + (hi32 << 2);
                float v = fmaxf(acc[mi][nj][q] + bhv, 0.f);
                size_t off = (size_t)row * 2048 + col;
                hnew_f32[off] = v;
                hnew_bf[off] = f2bf(v);
                csum += v;
            }
        }
        csum += __shfl_xor(csum, 32, 64);
        if (lane < 32) atomicAdd(&act_out[col], csum * (1.0f / 8192.0f));
    }
}

// ---------------------------------------------------------------------------
// GEMM3 (reverted to round-25 measured best: 16x16 shape, 3-bit involution)
// ---------------------------------------------------------------------------
#define G3_STA(KT, SET, BUF) do { \
    int uni_ = uA + ((KT) << 6) + ((SET) ? (2048 << 6) : 0); \
    u16* dst_ = g3A + (BUF) * 16384 + (SET) * 4096; \
    gload_lds16(Hn + uni_ + lo, dst_ + ((w << 3) << 6)); \
    gload_lds16(Hn + uni_ + lo + (2048 << 7), dst_ + ((128 + (w << 3)) << 6)); \
    } while (0)

#define G3_STB(KT, SET, BUF) do { \
    int uni_ = uB + ((KT) << 6) + ((SET) ? (2048 << 6) : 0); \
    gload_lds16(Wout + uni_ + lo, g3B + (BUF) * 8192 + (SET) * 4096 + ((w << 3) << 6)); \
    } while (0)

#define G3_RD_A(MQ, BUF) do { \
    _Pragma("unroll") for (int i = 0; i < 4; ++i) { \
        afr[i][0] = *(const bf16x8*)(fA0 + (BUF) * 32768 + (MQ) * 8192 + i * 2048); \
        afr[i][1] = *(const bf16x8*)(fA1 + (BUF) * 32768 + (MQ) * 8192 + i * 2048); \
    } } while (0)

#define G3_RD_B(BUF) do { \
    _Pragma("unroll") for (int n = 0; n < 2; ++n) { \
        bfr[n][0] = *(const bf16x8*)(fB0 + (BUF) * 16384 + n * 2048); \
        bfr[n][1] = *(const bf16x8*)(fB1 + (BUF) * 16384 + n * 2048); \
    } } while (0)

#define G3_MFMA(MQ) do { \
    _Pragma("unroll") for (int i = 0; i < 4; ++i) \
    _Pragma("unroll") for (int n = 0; n < 2; ++n) \
    _Pragma("unroll") for (int kk = 0; kk < 2; ++kk) \
        acc[(MQ)*4+i][n] = __builtin_amdgcn_mfma_f32_16x16x32_bf16( \
            afr[i][kk], bfr[n][kk], acc[(MQ)*4+i][n], 0, 0, 0); \
    } while (0)

__global__ __launch_bounds__(512, 1) void gemm3_k8(
    const u16* __restrict__ Hn, const u16* __restrict__ Wout,
    const float* __restrict__ bout, float* __restrict__ y) {
    __shared__ alignas(16) u16 lds[49152];
    u16* g3A = &lds[0];
    u16* g3B = &lds[32768];
    int orig = blockIdx.x;
    int wg = (orig & 7) * 32 + (orig >> 3);
    int bm = wg >> 3, bn = wg & 7;
    int t = threadIdx.x, lane = t & 63, w = t >> 6;
    int wm = w >> 2, wn = w & 3;
    int l15 = lane & 15, hi = lane >> 4;

    int r0 = t >> 3, c8 = t & 7;
    int swz = (c8 ^ (r0 & 7)) << 3;
    int lo = (r0 << 11) + swz;
    int uA = (bm << 8) << 11;
    int uB = (bn << 7) << 11;

    int cb0 = (hi ^ (l15 & 7)) << 4;
    int cb1 = ((4 + hi) ^ (l15 & 7)) << 4;
    const char* fA0 = (const char*)(g3A + (((wm << 7) + l15) << 6)) + cb0;
    const char* fA1 = (const char*)(g3A + (((wm << 7) + l15) << 6)) + cb1;
    const char* fB0 = (const char*)(g3B + (((wn << 5) + l15) << 6)) + cb0;
    const char* fB1 = (const char*)(g3B + (((wn << 5) + l15) << 6)) + cb1;

    f32x4 acc[8][2];
#pragma unroll
    for (int i = 0; i < 8; ++i)
#pragma unroll
        for (int j = 0; j < 2; ++j) acc[i][j] = (f32x4){0.f, 0.f, 0.f, 0.f};
    bf16x8 afr[4][2], bfr[2][2];

    G3_STA(0, 0, 0); G3_STB(0, 0, 0);
    G3_STA(0, 1, 0); G3_STB(0, 1, 0);
    G3_STA(1, 0, 1); G3_STB(1, 0, 1);
    asm volatile("s_waitcnt vmcnt(3)" ::: "memory");
    asm volatile("s_barrier" ::: "memory");

    for (int it = 0; it < 16; ++it) {
        int tb = it << 1;
        int t2 = tb + 2 < 31 ? tb + 2 : 31;
        int t3 = tb + 3 < 31 ? tb + 3 : 31;
        int t1 = tb + 1;

        G3_RD_B(0); G3_RD_A(0, 0);
        G3_STA(t1, 1, 1); G3_STB(t1, 1, 1);
        PHASE_MID(); G3_MFMA(0); BAREND();
        G3_RD_A(1, 0);
        G3_STA(t2, 0, 0); G3_STB(t2, 0, 0);
        PHASE_MID(); G3_MFMA(1); BAREND_VM3();
        G3_RD_B(1); G3_RD_A(0, 1);
        G3_STA(t2, 1, 0); G3_STB(t2, 1, 0);
        PHASE_MID(); G3_MFMA(0); BAREND();
        G3_RD_A(1, 1);
        G3_STA(t3, 0, 1); G3_STB(t3, 0, 1);
        PHASE_MID(); G3_MFMA(1); BAREND_VM3();
    }

    const int row0 = (bm << 8) + (wm << 7);
    const int col0 = (bn << 7) + (wn << 5);
#pragma unroll
    for (int n = 0; n < 2; ++n) {
        int col = col0 + (n << 4) + l15;
        float bv = bout[col];
#pragma unroll
        for (int m = 0; m < 8; ++m) {
#pragma unroll
            for (int r = 0; r < 4; ++r) {
                int row = row0 + (m << 4) + (hi << 2) + r;
                y[(size_t)row * 1024 + col] = acc[m][n][r] + bv;
            }
        }
    }
}

// ---------------------------------------------------------------------------
extern "C" void kernel_launch(void* const* d_in, const int* in_sizes, int n_in,
                              void* d_out, int out_size, void* d_ws, size_t ws_size,
                              hipStream_t stream) {
    const float* x     = (const float*)d_in[0];
    const float* h     = (const float*)d_in[1];
    const float* W_in  = (const float*)d_in[2];
    const float* W_hh  = (const float*)d_in[3];
    const float* b_h   = (const float*)d_in[4];
    const float* W_out = (const float*)d_in[5];
    const float* b_out = (const float*)d_in[6];

    float* out  = (float*)d_out;
    float* y    = out;
    float* hnew = out + 8388608;
    float* act  = out + 8388608 + 16777216;
    float* rec  = act + 2048;

    char* ws = (char*)d_ws;
    u16* x_bf    = (u16*)(ws);
    u16* h_bf    = (u16*)(ws + (16ull << 20));
    u16* win_bf  = (u16*)(ws + (48ull << 20));
    u16* whh_bf  = (u16*)(ws + (52ull << 20));
    u16* wout_bf = (u16*)(ws + (60ull << 20));
    u16* hn_bf   = (u16*)(ws + (64ull << 20));
    float* partial = (float*)(ws + (96ull << 20));  // 256 x 2048 f32 = 2 MB

    cvt_all_kernel<<<8448, 256, 0, stream>>>(x, x_bf, W_in, win_bf, W_hh, whh_bf,
                                             W_out, wout_bf, h, h_bf, partial, act);

    gemm12_k8<<<256, 512, 0, stream>>>(x_bf, win_bf, h_bf, whh_bf, b_h,
                                       hnew, hn_bf, act, partial, rec);
    gemm3_k8<<<256, 512, 0, stream>>>(hn_bf, wout_bf, b_out, y);
}

// Round 28
// 173.731 us; speedup vs baseline: 1.0234x; 1.0009x over previous
//
#include <hip/hip_runtime.h>
#include <hip/hip_bf16.h>

typedef unsigned short u16;
typedef __attribute__((ext_vector_type(8))) short bf16x8;
typedef __attribute__((ext_vector_type(4))) float f32x4;
typedef __attribute__((ext_vector_type(16))) float f32x16;

#define DEVINL __device__ __forceinline__

struct alignas(16) U8 { u16 v[8]; };

DEVINL u16 f2bf(float f) {
    unsigned int x = __float_as_uint(f);
    unsigned int r = (x + 0x7fffu + ((x >> 16) & 1u)) >> 16;
    return (u16)r;
}

DEVINL void gload_lds16(const void* g, void* l) {
    __builtin_amdgcn_global_load_lds(
        (const __attribute__((address_space(1))) void*)g,
        (__attribute__((address_space(3))) void*)l,
        16, 0, 0);
}

// ---------------------------------------------------------------------------
// conversion kernel v4 (frozen): blocks 0..255 = h (+ act zeroing); rest x/W
// ---------------------------------------------------------------------------
__global__ __launch_bounds__(256) void cvt_all_kernel(
    const float* __restrict__ x, u16* __restrict__ xb,
    const float* __restrict__ wi, u16* __restrict__ wib,
    const float* __restrict__ wh, u16* __restrict__ whb,
    const float* __restrict__ wo, u16* __restrict__ wob,
    const float* __restrict__ h, u16* __restrict__ hbf,
    float* __restrict__ partial, float* __restrict__ act) {
    int b = blockIdx.x;
    int t = threadIdx.x;
    if (b < 256) {
        if (t < 8) act[b * 8 + t] = 0.f;
        float cnt[8] = {0.f, 0.f, 0.f, 0.f, 0.f, 0.f, 0.f, 0.f};
#pragma unroll 4
        for (int r = 0; r < 32; ++r) {
            size_t off = ((size_t)(b * 32 + r)) * 2048 + t * 8;
            float4 a = *(const float4*)(h + off);
            float4 bb = *(const float4*)(h + off + 4);
            float vv[8] = {a.x, a.y, a.z, a.w, bb.x, bb.y, bb.z, bb.w};
            U8 u;
#pragma unroll
            for (int j = 0; j < 8; ++j) {
                u.v[j] = f2bf(vv[j]);
                cnt[j] += (fabsf(vv[j]) > 0.1f) ? 1.f : 0.f;
            }
            *(U8*)(hbf + off) = u;
        }
        float4 p0 = {cnt[0], cnt[1], cnt[2], cnt[3]};
        float4 p1 = {cnt[4], cnt[5], cnt[6], cnt[7]};
        *(float4*)(partial + (size_t)b * 2048 + t * 8) = p0;
        *(float4*)(partial + (size_t)b * 2048 + t * 8 + 4) = p1;
    } else {
        int i = (b - 256) * 256 + t;
        const float* src; u16* dst; int off;
        if (i < 1048576)       { src = x;  dst = xb;  off = i; }
        else if (i < 1310720)  { src = wi; dst = wib; off = i - 1048576; }
        else if (i < 1835008)  { src = wh; dst = whb; off = i - 1310720; }
        else                   { src = wo; dst = wob; off = i - 1835008; }
        const float4* p = (const float4*)src + (size_t)off * 2;
        float4 a = p[0], bb = p[1];
        U8 u;
        u.v[0] = f2bf(a.x);  u.v[1] = f2bf(a.y);  u.v[2] = f2bf(a.z);  u.v[3] = f2bf(a.w);
        u.v[4] = f2bf(bb.x); u.v[5] = f2bf(bb.y); u.v[6] = f2bf(bb.z); u.v[7] = f2bf(bb.w);
        *(U8*)(dst + (size_t)off * 8) = u;
    }
}

// ---------------------------------------------------------------------------
// staging helpers (frozen structure; swizzle passed in via lo)
// ---------------------------------------------------------------------------
DEVINL void stA(const u16* p, int uni, int lo, int ld, u16* dst, int w) {
    gload_lds16(p + uni + lo, dst + ((w << 3) << 6));
    gload_lds16(p + uni + lo + (ld << 7), dst + ((128 + (w << 3)) << 6));
}
DEVINL void stB(const u16* p, int uni, int lo, int ld, u16* dst, int w) {
    int d0 = ((w >> 2) << 6) + ((w & 3) << 3);
    gload_lds16(p + uni + lo, dst + (d0 << 6));
    gload_lds16(p + uni + lo + (ld << 7), dst + ((128 + d0) << 6));
}

struct SegU { const u16* pA; const u16* pB; int uA; int uB; int ld; int loA; int loB; };

DEVINL SegU segu(int kt, const u16* X, const u16* W1, const u16* H, const u16* W2,
                 int rbA, int rbB, int loA1, int loA2, int loB1, int loB2) {
    SegU s;
    if (kt < 16) {
        int k0 = kt << 6;
        s.pA = X; s.pB = W1; s.ld = 1024;
        s.uA = (rbA << 10) + k0; s.uB = (rbB << 10) + k0;
        s.loA = loA1; s.loB = loB1;
    } else {
        int k0 = (kt - 16) << 6;
        s.pA = H; s.pB = W2; s.ld = 2048;
        s.uA = (rbA << 11) + k0; s.uB = (rbB << 11) + k0;
        s.loA = loA2; s.loB = loB2;
    }
    return s;
}

#define STA(S, SET, BUF) stA((S).pA, (S).uA + ((SET) ? ((S).ld << 6) : 0), (S).loA, \
                             (S).ld, Alds + (BUF) * 16384 + (SET) * 4096, w)
#define STB(S, SET, BUF) stB((S).pB, (S).uB + ((SET) ? ((S).ld << 5) : 0), (S).loB, \
                             (S).ld, Blds + (BUF) * 16384 + (SET) * 2048, w)

// 32x32x16 fragment reads: per-kk base pointer + imm
#define RD_A32(MQ, BUF) do { \
    _Pragma("unroll") for (int kk = 0; kk < 4; ++kk) \
    _Pragma("unroll") for (int mi = 0; mi < 2; ++mi) \
        afr[mi][kk] = *(const bf16x8*)(fAk[kk] + (BUF) * 32768 + ((MQ)*2 + mi) * 4096); \
    } while (0)

#define RD_B_ALL32(BUF) do { \
    _Pragma("unroll") for (int kk = 0; kk < 4; ++kk) \
    _Pragma("unroll") for (int nj = 0; nj < 2; ++nj) \
        bfr[nj][kk] = *(const bf16x8*)(fBk[kk] + (BUF) * 32768 + nj * 4096); \
    } while (0)

// 16 MFMA 32x32x16: one m-half (2 mi) x 2 nj x 4 kk
#define MFMA_M32(MQ) do { \
    _Pragma("unroll") for (int mi = 0; mi < 2; ++mi) \
    _Pragma("unroll") for (int nj = 0; nj < 2; ++nj) \
    _Pragma("unroll") for (int kk = 0; kk < 4; ++kk) \
        acc[(MQ)*2 + mi][nj] = __builtin_amdgcn_mfma_f32_32x32x16_bf16( \
            afr[mi][kk], bfr[nj][kk], acc[(MQ)*2 + mi][nj], 0, 0, 0); \
    } while (0)

#define PHASE_MID() do { \
    asm volatile("s_waitcnt lgkmcnt(0)" ::: "memory"); \
    __builtin_amdgcn_sched_barrier(0); \
    __builtin_amdgcn_s_setprio(1); \
    } while (0)

#define BAREND() do { \
    __builtin_amdgcn_s_setprio(0); \
    __builtin_amdgcn_sched_barrier(0); \
    asm volatile("s_barrier" ::: "memory"); \
    } while (0)

#define BAREND_VM() do { \
    __builtin_amdgcn_s_setprio(0); \
    __builtin_amdgcn_sched_barrier(0); \
    asm volatile("s_waitcnt vmcnt(4)" ::: "memory"); \
    asm volatile("s_barrier" ::: "memory"); \
    } while (0)

#define BAREND_VM3() do { \
    __builtin_amdgcn_s_setprio(0); \
    __builtin_amdgcn_sched_barrier(0); \
    asm volatile("s_waitcnt vmcnt(3)" ::: "memory"); \
    asm volatile("s_barrier" ::: "memory"); \
    } while (0)

// ---------------------------------------------------------------------------
// GEMM12 with 32x32x16 MFMA, conflict-free 5-bit involution (frozen, measured)
// ---------------------------------------------------------------------------
__global__ __launch_bounds__(512, 2) void gemm12_k8(
    const u16* __restrict__ Xbf, const u16* __restrict__ Win,
    const u16* __restrict__ Hbf, const u16* __restrict__ Whh,
    const float* __restrict__ bh,
    float* __restrict__ hnew_f32, u16* __restrict__ hnew_bf,
    float* __restrict__ act_out,
    const float* __restrict__ partial, float* __restrict__ rec_out) {
    __shared__ alignas(16) u16 lds[4][16384];  // [A0|A1|B0|B1] = 128 KB
    u16* Alds = &lds[0][0];
    u16* Blds = &lds[2][0];
    int orig = blockIdx.x;
    int wg = (orig & 7) * 32 + (orig >> 3);    // XCD swizzle
    int bm = wg >> 3, bn = wg & 7;
    int t = threadIdx.x, lane = t & 63, w = t >> 6;
    int wm = w >> 2, wn = w & 3;
    int l31 = lane & 31, hi32 = lane >> 5;
    int rbA = bm << 8, rbB = bn << 8;

    // folded rec final reduce: block handles cols [orig*8, orig*8+8)
    {
        int col = (orig << 3) + (t >> 6);
        float s = partial[(size_t)lane * 2048 + col]
                + partial[(size_t)(lane + 64) * 2048 + col]
                + partial[(size_t)(lane + 128) * 2048 + col]
                + partial[(size_t)(lane + 192) * 2048 + col];
#pragma unroll
        for (int o = 1; o < 64; o <<= 1) s += __shfl_xor(s, o, 64);
        if (lane == 0) rec_out[col] = s * (1.0f / 8192.0f);
    }

    // staging lane offsets; 5-bit involution, r0-invariant for both ops
    int r0 = t >> 3, c8 = t & 7;
    int swz = ((c8 ^ (r0 & 7) ^ ((r0 >> 3) & 3))) << 3;
    int arB0 = ((r0 >> 5) << 6) + (r0 & 31);
    int loA1 = (r0 << 10) + swz, loA2 = (r0 << 11) + swz;
    int loB1 = (arB0 << 10) + swz, loB2 = (arB0 << 11) + swz;

    // 32x32 fragment base pointers, one per kk (read swizzle matches staging)
    const char* fAk[4];
    const char* fBk[4];
#pragma unroll
    for (int kk = 0; kk < 4; ++kk) {
        int cb = ((kk << 1) + hi32) ^ (l31 & 7) ^ ((l31 >> 3) & 3);
        fAk[kk] = (const char*)(Alds + (((wm << 7) + l31) << 6)) + (cb << 4);
        fBk[kk] = (const char*)(Blds + (((wn << 6) + l31) << 6)) + (cb << 4);
    }

    f32x16 acc[4][2];
    f32x16 zf = {};
#pragma unroll
    for (int i = 0; i < 4; ++i)
#pragma unroll
        for (int j = 0; j < 2; ++j) acc[i][j] = zf;
    bf16x8 afr[2][4], bfr[2][4];

    // prologue (frozen ledger): 12 loads, wait to <=4
    {
        SegU s0 = segu(0, Xbf, Win, Hbf, Whh, rbA, rbB, loA1, loA2, loB1, loB2);
        SegU s1 = segu(1, Xbf, Win, Hbf, Whh, rbA, rbB, loA1, loA2, loB1, loB2);
        STA(s0, 0, 0); STB(s0, 0, 0);
        STA(s0, 1, 0); STB(s0, 1, 0);
        STA(s1, 0, 1); STB(s1, 0, 1);
    }
    asm volatile("s_waitcnt vmcnt(4)" ::: "memory");
    asm volatile("s_barrier" ::: "memory");

    for (int it = 0; it < 24; ++it) {
        int tb = it << 1;
        int t2 = tb + 2 < 47 ? tb + 2 : 47;
        int t3 = tb + 3 < 47 ? tb + 3 : 47;
        SegU s1 = segu(tb + 1, Xbf, Win, Hbf, Whh, rbA, rbB, loA1, loA2, loB1, loB2);
        SegU s2 = segu(t2,     Xbf, Win, Hbf, Whh, rbA, rbB, loA1, loA2, loB1, loB2);
        SegU s3 = segu(t3,     Xbf, Win, Hbf, Whh, rbA, rbB, loA1, loA2, loB1, loB2);

        // phase A: tile tb (buf0), m0; stage (tb+1,set1)->buf1
        RD_B_ALL32(0); RD_A32(0, 0);
        STA(s1, 1, 1); STB(s1, 1, 1);
        PHASE_MID(); MFMA_M32(0); BAREND();
        // phase B: tile tb, m1; stage (tb+2,set0)->buf0
        RD_A32(1, 0);
        STA(s2, 0, 0); STB(s2, 0, 0);
        PHASE_MID(); MFMA_M32(1); BAREND_VM();
        // phase C: tile tb+1 (buf1), m0; stage (tb+2,set1)->buf0
        RD_B_ALL32(1); RD_A32(0, 1);
        STA(s2, 1, 0); STB(s2, 1, 0);
        PHASE_MID(); MFMA_M32(0); BAREND();
        // phase D: tile tb+1, m1; stage (tb+3,set0)->buf1
        RD_A32(1, 1);
        STA(s3, 0, 1); STB(s3, 0, 1);
        PHASE_MID(); MFMA_M32(1); BAREND_VM();
    }

    // epilogue: 32x32 C/D layout: col = lane&31, row = (q&3)+8*(q>>2)+4*(lane>>5)
    const int row0 = (bm << 8) + (wm << 7);
    const int col0 = (bn << 8) + (wn << 6);
#pragma unroll
    for (int nj = 0; nj < 2; ++nj) {
        int col = col0 + (nj << 5) + l31;
        float bhv = bh[col];
        float csum = 0.f;
#pragma unroll
        for (int mi = 0; mi < 4; ++mi) {
#pragma unroll
            for (int q = 0; q < 16; ++q) {
                int row = row0 + (mi << 5) + (q & 3) + ((q >> 2) << 3) + (hi32 << 2);
                float v = fmaxf(acc[mi][nj][q] + bhv, 0.f);
                size_t off = (size_t)row * 2048 + col;
                hnew_f32[off] = v;
                hnew_bf[off] = f2bf(v);
                csum += v;
            }
        }
        csum += __shfl_xor(csum, 32, 64);
        if (lane < 32) atomicAdd(&act_out[col], csum * (1.0f / 8192.0f));
    }
}

// ---------------------------------------------------------------------------
// GEMM3 (round-25 measured best: 16x16 shape, 3-bit involution)
// ---------------------------------------------------------------------------
#define G3_STA(KT, SET, BUF) do { \
    int uni_ = uA + ((KT) << 6) + ((SET) ? (2048 << 6) : 0); \
    u16* dst_ = g3A + (BUF) * 16384 + (SET) * 4096; \
    gload_lds16(Hn + uni_ + lo, dst_ + ((w << 3) << 6)); \
    gload_lds16(Hn + uni_ + lo + (2048 << 7), dst_ + ((128 + (w << 3)) << 6)); \
    } while (0)

#define G3_STB(KT, SET, BUF) do { \
    int uni_ = uB + ((KT) << 6) + ((SET) ? (2048 << 6) : 0); \
    gload_lds16(Wout + uni_ + lo, g3B + (BUF) * 8192 + (SET) * 4096 + ((w << 3) << 6)); \
    } while (0)

#define G3_RD_A(MQ, BUF) do { \
    _Pragma("unroll") for (int i = 0; i < 4; ++i) { \
        afr[i][0] = *(const bf16x8*)(fA0 + (BUF) * 32768 + (MQ) * 8192 + i * 2048); \
        afr[i][1] = *(const bf16x8*)(fA1 + (BUF) * 32768 + (MQ) * 8192 + i * 2048); \
    } } while (0)

#define G3_RD_B(BUF) do { \
    _Pragma("unroll") for (int n = 0; n < 2; ++n) { \
        bfr[n][0] = *(const bf16x8*)(fB0 + (BUF) * 16384 + n * 2048); \
        bfr[n][1] = *(const bf16x8*)(fB1 + (BUF) * 16384 + n * 2048); \
    } } while (0)

#define G3_MFMA(MQ) do { \
    _Pragma("unroll") for (int i = 0; i < 4; ++i) \
    _Pragma("unroll") for (int n = 0; n < 2; ++n) \
    _Pragma("unroll") for (int kk = 0; kk < 2; ++kk) \
        acc[(MQ)*4+i][n] = __builtin_amdgcn_mfma_f32_16x16x32_bf16( \
            afr[i][kk], bfr[n][kk], acc[(MQ)*4+i][n], 0, 0, 0); \
    } while (0)

__global__ __launch_bounds__(512, 1) void gemm3_k8(
    const u16* __restrict__ Hn, const u16* __restrict__ Wout,
    const float* __restrict__ bout, float* __restrict__ y) {
    __shared__ alignas(16) u16 lds[49152];
    u16* g3A = &lds[0];
    u16* g3B = &lds[32768];
    int orig = blockIdx.x;
    int wg = (orig & 7) * 32 + (orig >> 3);
    int bm = wg >> 3, bn = wg & 7;
    int t = threadIdx.x, lane = t & 63, w = t >> 6;
    int wm = w >> 2, wn = w & 3;
    int l15 = lane & 15, hi = lane >> 4;

    int r0 = t >> 3, c8 = t & 7;
    int swz = (c8 ^ (r0 & 7)) << 3;
    int lo = (r0 << 11) + swz;
    int uA = (bm << 8) << 11;
    int uB = (bn << 7) << 11;

    int cb0 = (hi ^ (l15 & 7)) << 4;
    int cb1 = ((4 + hi) ^ (l15 & 7)) << 4;
    const char* fA0 = (const char*)(g3A + (((wm << 7) + l15) << 6)) + cb0;
    const char* fA1 = (const char*)(g3A + (((wm << 7) + l15) << 6)) + cb1;
    const char* fB0 = (const char*)(g3B + (((wn << 5) + l15) << 6)) + cb0;
    const char* fB1 = (const char*)(g3B + (((wn << 5) + l15) << 6)) + cb1;

    f32x4 acc[8][2];
#pragma unroll
    for (int i = 0; i < 8; ++i)
#pragma unroll
        for (int j = 0; j < 2; ++j) acc[i][j] = (f32x4){0.f, 0.f, 0.f, 0.f};
    bf16x8 afr[4][2], bfr[2][2];

    G3_STA(0, 0, 0); G3_STB(0, 0, 0);
    G3_STA(0, 1, 0); G3_STB(0, 1, 0);
    G3_STA(1, 0, 1); G3_STB(1, 0, 1);
    asm volatile("s_waitcnt vmcnt(3)" ::: "memory");
    asm volatile("s_barrier" ::: "memory");

    for (int it = 0; it < 16; ++it) {
        int tb = it << 1;
        int t2 = tb + 2 < 31 ? tb + 2 : 31;
        int t3 = tb + 3 < 31 ? tb + 3 : 31;
        int t1 = tb + 1;

        G3_RD_B(0); G3_RD_A(0, 0);
        G3_STA(t1, 1, 1); G3_STB(t1, 1, 1);
        PHASE_MID(); G3_MFMA(0); BAREND();
        G3_RD_A(1, 0);
        G3_STA(t2, 0, 0); G3_STB(t2, 0, 0);
        PHASE_MID(); G3_MFMA(1); BAREND_VM3();
        G3_RD_B(1); G3_RD_A(0, 1);
        G3_STA(t2, 1, 0); G3_STB(t2, 1, 0);
        PHASE_MID(); G3_MFMA(0); BAREND();
        G3_RD_A(1, 1);
        G3_STA(t3, 0, 1); G3_STB(t3, 0, 1);
        PHASE_MID(); G3_MFMA(1); BAREND_VM3();
    }

    const int row0 = (bm << 8) + (wm << 7);
    const int col0 = (bn << 7) + (wn << 5);
#pragma unroll
    for (int n = 0; n < 2; ++n) {
        int col = col0 + (n << 4) + l15;
        float bv = bout[col];
#pragma unroll
        for (int m = 0; m < 8; ++m) {
#pragma unroll
            for (int r = 0; r < 4; ++r) {
                int row = row0 + (m << 4) + (hi << 2) + r;
                y[(size_t)row * 1024 + col] = acc[m][n][r] + bv;
            }
        }
    }
}

// ---------------------------------------------------------------------------
extern "C" void kernel_launch(void* const* d_in, const int* in_sizes, int n_in,
                              void* d_out, int out_size, void* d_ws, size_t ws_size,
                              hipStream_t stream) {
    const float* x     = (const float*)d_in[0];
    const float* h     = (const float*)d_in[1];
    const float* W_in  = (const float*)d_in[2];
    const float* W_hh  = (const float*)d_in[3];
    const float* b_h   = (const float*)d_in[4];
    const float* W_out = (const float*)d_in[5];
    const float* b_out = (const float*)d_in[6];

    float* out  = (float*)d_out;
    float* y    = out;
    float* hnew = out + 8388608;
    float* act  = out + 8388608 + 16777216;
    float* rec  = act + 2048;

    char* ws = (char*)d_ws;
    u16* x_bf    = (u16*)(ws);
    u16* h_bf    = (u16*)(ws + (16ull << 20));
    u16* win_bf  = (u16*)(ws + (48ull << 20));
    u16* whh_bf  = (u16*)(ws + (52ull << 20));
    u16* wout_bf = (u16*)(ws + (60ull << 20));
    u16* hn_bf   = (u16*)(ws + (64ull << 20));
    float* partial = (float*)(ws + (96ull << 20));  // 256 x 2048 f32 = 2 MB

    cvt_all_kernel<<<8448, 256, 0, stream>>>(x, x_bf, W_in, win_bf, W_hh, whh_bf,
                                             W_out, wout_bf, h, h_bf, partial, act);

    gemm12_k8<<<256, 512, 0, stream>>>(x_bf, win_bf, h_bf, whh_bf, b_h,
                                       hnew, hn_bf, act, partial, rec);
    gemm3_k8<<<256, 512, 0, stream>>>(hn_bf, wout_bf, b_out, y);
}